// Round 8
// baseline (163.695 us; speedup 1.0000x reference)
//
#include <hip/hip_runtime.h>
#include <hip/hip_fp16.h>
#include <math.h>

#define Bn 512
#define Ln 200
#define En 64
#define Hn 4
#define Dn 16
#define NT13 13           // ceil(200/16)
#define RMAX 208          // 13*16
#define KS 36             // Kh/Qh row stride (halves): 72 B (t*18 words: 16 distinct banks)
#define VS 212            // Vt row stride (halves): 424 B (row*106 words: 16 distinct banks)

typedef _Float16 __f16;
typedef __f16 f16x4 __attribute__((ext_vector_type(4)));
typedef __f16 f16x8 __attribute__((ext_vector_type(8)));
typedef float f32x4 __attribute__((ext_vector_type(4)));

__device__ __forceinline__ f16x8 pack8s(float4 a, float4 b, float4 pa, float4 pb) {
    f16x8 r;
    r[0] = (__f16)(a.x + pa.x); r[1] = (__f16)(a.y + pa.y);
    r[2] = (__f16)(a.z + pa.z); r[3] = (__f16)(a.w + pa.w);
    r[4] = (__f16)(b.x + pb.x); r[5] = (__f16)(b.y + pb.y);
    r[6] = (__f16)(b.z + pb.z); r[7] = (__f16)(b.w + pb.w);
    return r;
}
__device__ __forceinline__ f16x8 pack8(float4 a, float4 b) {
    f16x8 r;
    r[0] = (__f16)a.x; r[1] = (__f16)a.y; r[2] = (__f16)a.z; r[3] = (__f16)a.w;
    r[4] = (__f16)b.x; r[5] = (__f16)b.y; r[6] = (__f16)b.z; r[7] = (__f16)b.w;
    return r;
}

// ============ Fused: projection + attention + pooling. Block = (b, head-pair), 512 threads ============
// 8 waves: proj tiles rt = {wave, wave+8} (<=2 serial tiles, tile1 globals prefetched under
// tile0 MFMA); attention: head = wave>>2, query-tile pairs p = (wave&3), +4 (<=2 serial pairs),
// kt-loop software-pipelined (next K/V fragments loaded before current compute).
// A-frags come straight from global (no LDS x tile). S^T=K*Q^T C-layout == PV B-layout: no transforms.
__global__ __launch_bounds__(512, 4) void fused_kernel(
    const float* __restrict__ input, const int* __restrict__ mask,
    const float* __restrict__ pos_enc,
    const float* __restrict__ Wk, const float* __restrict__ bk,
    const float* __restrict__ Wv, const float* __restrict__ bv,
    const float* __restrict__ Wq, const float* __restrict__ bq,
    float* __restrict__ pooled)
{
    __shared__ __align__(16) __f16 Kh[RMAX * KS];   // 15.0 KB  K[t][2*16]
    __shared__ __align__(16) __f16 Qh[RMAX * KS];   // 15.0 KB  Q[t][2*16]
    __shared__ __align__(16) __f16 Vt[32 * VS];     // 13.6 KB  V^T[vd][t]
    __shared__ float red[8][16];
    __shared__ int cnt_red[8];

    const int tid  = threadIdx.x;
    const int b    = blockIdx.x >> 1, hp = blockIdx.x & 1;
    const int wave = tid >> 6, lane = tid & 63;
    const int quad = lane >> 4, ln16 = lane & 15;

    // ---- issue mask load immediately ----
    const int mv = (tid < Ln) ? mask[b * Ln + tid] : 0;

    // ---- proj tile0 global prefetch (R0 <= 127: always valid) ----
    const float4* in4 = (const float4*)(input + (size_t)b * Ln * En);
    const float4* pe4 = (const float4*)pos_enc;
    const int rt0 = wave, rt1 = wave + 8;
    const int R0 = rt0 * 16 + ln16, R1 = rt1 * 16 + ln16;
    const int c4 = quad * 2;
    float4 x00 = in4[R0 * 16 + c4],     x01 = in4[R0 * 16 + c4 + 1];
    float4 x02 = in4[R0 * 16 + 8 + c4], x03 = in4[R0 * 16 + 8 + c4 + 1];
    float4 p00 = pe4[R0 * 16 + c4],     p01 = pe4[R0 * 16 + c4 + 1];
    float4 p02 = pe4[R0 * 16 + 8 + c4], p03 = pe4[R0 * 16 + 8 + c4 + 1];

    // ---- weight B-fragments (L2-hot) + biases ----
    f16x8 bfr[3][2][2];
    #pragma unroll
    for (int m = 0; m < 3; ++m) {
        const float* W = (m == 0) ? Wk : (m == 1) ? Wv : Wq;
        #pragma unroll
        for (int ct = 0; ct < 2; ++ct)
            #pragma unroll
            for (int ks = 0; ks < 2; ++ks) {
                const float4* wp = (const float4*)(W + (size_t)(hp * 32 + ct * 16 + ln16) * 64) + (ks * 8 + quad * 2);
                bfr[m][ct][ks] = pack8(wp[0], wp[1]);
            }
    }
    float bkv[2], bvv[2], bqv[2];
    #pragma unroll
    for (int ct = 0; ct < 2; ++ct) {
        int cg = hp * 32 + ct * 16 + ln16;
        bkv[ct] = bk[cg]; bvv[ct] = bv[cg]; bqv[ct] = bq[cg];
    }

    // ---- tile0 A-frags; then issue tile1 loads (hidden under tile0 MFMA) ----
    f16x8 af0[2];
    af0[0] = pack8s(x00, x01, p00, p01);
    af0[1] = pack8s(x02, x03, p02, p03);

    const bool t1ok = (rt1 < NT13);
    const bool v1   = t1ok && (R1 < Ln);
    float4 x10 = {0,0,0,0}, x11 = {0,0,0,0}, x12 = {0,0,0,0}, x13 = {0,0,0,0};
    float4 p10 = {0,0,0,0}, p11 = {0,0,0,0}, p12 = {0,0,0,0}, p13 = {0,0,0,0};
    if (v1) {
        x10 = in4[R1 * 16 + c4];     x11 = in4[R1 * 16 + c4 + 1];
        x12 = in4[R1 * 16 + 8 + c4]; x13 = in4[R1 * 16 + 8 + c4 + 1];
        p10 = pe4[R1 * 16 + c4];     p11 = pe4[R1 * 16 + c4 + 1];
        p12 = pe4[R1 * 16 + 8 + c4]; p13 = pe4[R1 * 16 + 8 + c4 + 1];
    }

    // ---- tile0 MFMA + epilogue ----
    {
        f32x4 acc[3][2];
        #pragma unroll
        for (int m = 0; m < 3; ++m)
            #pragma unroll
            for (int ct = 0; ct < 2; ++ct) acc[m][ct] = (f32x4){0,0,0,0};
        #pragma unroll
        for (int ks = 0; ks < 2; ++ks)
            #pragma unroll
            for (int m = 0; m < 3; ++m)
                #pragma unroll
                for (int ct = 0; ct < 2; ++ct)
                    acc[m][ct] = __builtin_amdgcn_mfma_f32_16x16x32_f16(af0[ks], bfr[m][ct][ks], acc[m][ct], 0, 0, 0);
        #pragma unroll
        for (int ct = 0; ct < 2; ++ct) {
            #pragma unroll
            for (int j = 0; j < 4; ++j) {
                int t = rt0 * 16 + quad * 4 + j;
                Kh[t * KS + ct * 16 + ln16] = (__f16)(acc[0][ct][j] + bkv[ct]);
                Qh[t * KS + ct * 16 + ln16] = (__f16)((acc[2][ct][j] + bqv[ct]) * 0.25f);
            }
            f16x4 vp;
            #pragma unroll
            for (int j = 0; j < 4; ++j) vp[j] = (__f16)(acc[1][ct][j] + bvv[ct]);
            *(f16x4*)(Vt + (ct * 16 + ln16) * VS + rt0 * 16 + quad * 4) = vp;
        }
    }
    // ---- tile1 MFMA + epilogue (wave-uniform guard) ----
    if (t1ok) {
        f16x8 af1[2];
        af1[0] = pack8s(x10, x11, p10, p11);
        af1[1] = pack8s(x12, x13, p12, p13);
        f32x4 acc[3][2];
        #pragma unroll
        for (int m = 0; m < 3; ++m)
            #pragma unroll
            for (int ct = 0; ct < 2; ++ct) acc[m][ct] = (f32x4){0,0,0,0};
        #pragma unroll
        for (int ks = 0; ks < 2; ++ks)
            #pragma unroll
            for (int m = 0; m < 3; ++m)
                #pragma unroll
                for (int ct = 0; ct < 2; ++ct)
                    acc[m][ct] = __builtin_amdgcn_mfma_f32_16x16x32_f16(af1[ks], bfr[m][ct][ks], acc[m][ct], 0, 0, 0);
        #pragma unroll
        for (int ct = 0; ct < 2; ++ct) {
            #pragma unroll
            for (int j = 0; j < 4; ++j) {
                int t = rt1 * 16 + quad * 4 + j;
                Kh[t * KS + ct * 16 + ln16] = (__f16)(acc[0][ct][j] + bkv[ct]);
                Qh[t * KS + ct * 16 + ln16] = (__f16)((acc[2][ct][j] + bqv[ct]) * 0.25f);
            }
            f16x4 vp;
            #pragma unroll
            for (int j = 0; j < 4; ++j) vp[j] = (__f16)(acc[1][ct][j] + bvv[ct]);
            *(f16x4*)(Vt + (ct * 16 + ln16) * VS + rt1 * 16 + quad * 4) = vp;
        }
    }

    // ---- mask popcount ----
    int c = (mv != 0) ? 1 : 0;
    #pragma unroll
    for (int off = 32; off; off >>= 1) c += __shfl_down(c, off, 64);
    if (lane == 0) cnt_red[wave] = c;
    __syncthreads();   // proj LDS + cnt_red visible
    int len = 0;
    #pragma unroll
    for (int w = 0; w < 8; ++w) len += cnt_red[w];
    const int nt = (len + 15) >> 4;

    // ---- attention: head hl = wave>>2; pairs p = (wave&3), +4; kt-loop pipelined ----
    const int hl = wave >> 2;
    const int hoff = hl * 16;
    const int npair = (nt + 1) >> 1;
    f32x4 pool = {0.f, 0.f, 0.f, 0.f};

    for (int p = (wave & 3); p < npair; p += 4) {
        const int qt0 = 2 * p, qt1 = 2 * p + 1;
        const int qr1 = min(qt1 * 16 + ln16, RMAX - 1);
        const f16x4 qf0 = *(const f16x4*)(Qh + (qt0 * 16 + ln16) * KS + hoff + quad * 4);
        const f16x4 qf1 = *(const f16x4*)(Qh + qr1 * KS + hoff + quad * 4);
        f32x4 o20 = {0,0,0,0}, o21 = {0,0,0,0};
        float l0 = 0.f, l1 = 0.f;

        f16x4 kf = *(const f16x4*)(Kh + ln16 * KS + hoff + quad * 4);
        f16x4 vf = *(const f16x4*)(Vt + (hoff + ln16) * VS + quad * 4);

        for (int kt = 0; kt < nt - 1; ++kt) {     // full tiles
            const f16x4 kfn = *(const f16x4*)(Kh + ((kt + 1) * 16 + ln16) * KS + hoff + quad * 4);
            const f16x4 vfn = *(const f16x4*)(Vt + (hoff + ln16) * VS + (kt + 1) * 16 + quad * 4);
            f32x4 s0 = __builtin_amdgcn_mfma_f32_16x16x16f16(kf, qf0, (f32x4){0,0,0,0}, 0, 0, 0);
            f32x4 s1 = __builtin_amdgcn_mfma_f32_16x16x16f16(kf, qf1, (f32x4){0,0,0,0}, 0, 0, 0);
            f16x4 pf0, pf1;
            #pragma unroll
            for (int j = 0; j < 4; ++j) {
                float q0 = __expf(fminf(s0[j], 10.f));
                float q1 = __expf(fminf(s1[j], 10.f));
                l0 += q0; l1 += q1;
                pf0[j] = (__f16)q0; pf1[j] = (__f16)q1;
            }
            o20 = __builtin_amdgcn_mfma_f32_16x16x16f16(vf, pf0, o20, 0, 0, 0);
            o21 = __builtin_amdgcn_mfma_f32_16x16x16f16(vf, pf1, o21, 0, 0, 0);
            kf = kfn; vf = vfn;
        }
        {   // last tile: mask keys >= len
            const int kbase = (nt - 1) * 16 + quad * 4;
            f32x4 s0 = __builtin_amdgcn_mfma_f32_16x16x16f16(kf, qf0, (f32x4){0,0,0,0}, 0, 0, 0);
            f32x4 s1 = __builtin_amdgcn_mfma_f32_16x16x16f16(kf, qf1, (f32x4){0,0,0,0}, 0, 0, 0);
            f16x4 pf0, pf1;
            #pragma unroll
            for (int j = 0; j < 4; ++j) {
                const bool kok = (kbase + j) < len;
                float q0 = kok ? __expf(fminf(s0[j], 10.f)) : 0.f;
                float q1 = kok ? __expf(fminf(s1[j], 10.f)) : 0.f;
                l0 += q0; l1 += q1;
                pf0[j] = (__f16)q0; pf1[j] = (__f16)q1;
            }
            o20 = __builtin_amdgcn_mfma_f32_16x16x16f16(vf, pf0, o20, 0, 0, 0);
            o21 = __builtin_amdgcn_mfma_f32_16x16x16f16(vf, pf1, o21, 0, 0, 0);
        }

        l0 += __shfl_xor(l0, 16, 64); l0 += __shfl_xor(l0, 32, 64);
        l1 += __shfl_xor(l1, 16, 64); l1 += __shfl_xor(l1, 32, 64);
        const float rs0 = (qt0 * 16 + ln16 < len) ? 1.f / l0 : 0.f;
        const float rs1 = (qt1 * 16 + ln16 < len) ? 1.f / l1 : 0.f;
        #pragma unroll
        for (int j = 0; j < 4; ++j)
            pool[j] = fmaf(o20[j], rs0, fmaf(o21[j], rs1, pool[j]));
    }

    // ---- reduce pool over 16 q-lanes; combine 4 waves/head; write ----
    #pragma unroll
    for (int j = 0; j < 4; ++j) {
        #pragma unroll
        for (int off = 1; off < 16; off <<= 1) pool[j] += __shfl_xor(pool[j], off, 64);
    }
    if (ln16 == 0) {
        #pragma unroll
        for (int j = 0; j < 4; ++j) red[wave][quad * 4 + j] = pool[j];
    }
    __syncthreads();
    if (tid < 32) {
        int hl2 = tid >> 4, vd = tid & 15;
        float sres = red[hl2 * 4][vd] + red[hl2 * 4 + 1][vd]
                   + red[hl2 * 4 + 2][vd] + red[hl2 * 4 + 3][vd];
        pooled[b * En + hp * 32 + hl2 * 16 + vd] = sres / ((float)len + 1e-8f);
    }
}

// ======================= final projection: out[b,:] = pooled[b,:] @ Wf^T + bf =======================
__global__ __launch_bounds__(256) void final_kernel(
    const float* __restrict__ pooled, const float* __restrict__ Wf,
    const float* __restrict__ bf_, float* __restrict__ out)
{
    __shared__ float Wfs[En * 65];
    __shared__ float accs[4][En];
    const int tid = threadIdx.x, wave = tid >> 6, lane = tid & 63;
    const int b = blockIdx.x * 4 + wave;

    const float4* Wf4 = (const float4*)Wf;
    for (int idx4 = tid; idx4 < En * 16; idx4 += 256) {
        int e = idx4 >> 4, i4 = idx4 & 15;
        float4 w = Wf4[idx4];
        Wfs[e * 65 + i4 * 4 + 0] = w.x;
        Wfs[e * 65 + i4 * 4 + 1] = w.y;
        Wfs[e * 65 + i4 * 4 + 2] = w.z;
        Wfs[e * 65 + i4 * 4 + 3] = w.w;
    }
    accs[wave][lane] = pooled[b * En + lane];
    __syncthreads();

    float s = 0.f;
    #pragma unroll
    for (int i = 0; i < En; ++i)
        s = fmaf(accs[wave][i], Wfs[lane * 65 + i], s);
    out[b * En + lane] = s + bf_[lane];
}

extern "C" void kernel_launch(void* const* d_in, const int* in_sizes, int n_in,
                              void* d_out, int out_size, void* d_ws, size_t ws_size,
                              hipStream_t stream) {
    const float* input   = (const float*)d_in[0];
    const int*   mask    = (const int*)  d_in[1];
    const float* pos_enc = (const float*)d_in[2];
    const float* Wk      = (const float*)d_in[3];
    const float* bk      = (const float*)d_in[4];
    const float* Wv      = (const float*)d_in[5];
    const float* bv      = (const float*)d_in[6];
    const float* Wq      = (const float*)d_in[7];
    const float* bq      = (const float*)d_in[8];
    const float* Wf      = (const float*)d_in[9];
    const float* bf      = (const float*)d_in[10];

    float* pooled = (float*)d_ws;     // [B,64] fp32 = 131 KB
    float* out    = (float*)d_out;

    fused_kernel<<<Bn * 2, 512, 0, stream>>>(input, mask, pos_enc,
                                             Wk, bk, Wv, bv, Wq, bq, pooled);
    final_kernel<<<Bn / 4, 256, 0, stream>>>(pooled, Wf, bf, out);
}

// Round 9
// 148.898 us; speedup vs baseline: 1.0994x; 1.0994x over previous
//
#include <hip/hip_runtime.h>
#include <hip/hip_fp16.h>
#include <math.h>

#define Bn 512
#define Ln 200
#define En 64
#define Hn 4
#define Dn 16
#define NT13 13           // ceil(200/16)
#define RMAX 208          // 13*16
#define KS 36             // Kh/Qh row stride (halves): 72 B
#define VS 212            // Vt row stride (halves): 424 B

typedef _Float16 __f16;
typedef __f16 f16x4 __attribute__((ext_vector_type(4)));
typedef __f16 f16x8 __attribute__((ext_vector_type(8)));
typedef float f32x4 __attribute__((ext_vector_type(4)));

__device__ __forceinline__ f16x8 pack8s(float4 a, float4 b, float4 pa, float4 pb) {
    f16x8 r;
    r[0] = (__f16)(a.x + pa.x); r[1] = (__f16)(a.y + pa.y);
    r[2] = (__f16)(a.z + pa.z); r[3] = (__f16)(a.w + pa.w);
    r[4] = (__f16)(b.x + pb.x); r[5] = (__f16)(b.y + pb.y);
    r[6] = (__f16)(b.z + pb.z); r[7] = (__f16)(b.w + pb.w);
    return r;
}
__device__ __forceinline__ f16x8 pack8(float4 a, float4 b) {
    f16x8 r;
    r[0] = (__f16)a.x; r[1] = (__f16)a.y; r[2] = (__f16)a.z; r[3] = (__f16)a.w;
    r[4] = (__f16)b.x; r[5] = (__f16)b.y; r[6] = (__f16)b.z; r[7] = (__f16)b.w;
    return r;
}

// ============ Fully fused: projection + attention + pooling + Wf, block = (b, head-pair) ============
// 8 waves, 512 threads, __launch_bounds__(512,2): VGPR cap 256 -> NO scratch spill (R8's bug).
// Proj: wave stages tiles {wave, wave+8}; tile1 x prefetched in regs under tile0 MFMA
// (pos_enc is L2-hot, loaded late). Attention: head = wave>>2, q-tile pairs (wave&3)+4k,
// kt-loop software-pipelined. S^T=K*Q^T C-layout == PV B-layout: no transforms.
// Epilogue: block's 32 pooled dims -> out[b, 0..63] partial via Wf + atomicAdd (d_out pre-zeroed).
__global__ __launch_bounds__(512, 2) void fused_kernel(
    const float* __restrict__ input, const int* __restrict__ mask,
    const float* __restrict__ pos_enc,
    const float* __restrict__ Wk, const float* __restrict__ bk,
    const float* __restrict__ Wv, const float* __restrict__ bv,
    const float* __restrict__ Wq, const float* __restrict__ bq,
    const float* __restrict__ Wf, const float* __restrict__ bf_,
    float* __restrict__ out)
{
    __shared__ __align__(16) __f16 Kh[RMAX * KS];   // 15.0 KB  K[t][2*16]
    __shared__ __align__(16) __f16 Qh[RMAX * KS];   // 15.0 KB  Q[t][2*16]
    __shared__ __align__(16) __f16 Vt[32 * VS];     // 13.6 KB  V^T[vd][t]
    __shared__ float red[8][16];
    __shared__ float ph[32];
    __shared__ int cnt_red[8];

    const int tid  = threadIdx.x;
    const int b    = blockIdx.x >> 1, hp = blockIdx.x & 1;
    const int wave = tid >> 6, lane = tid & 63;
    const int quad = lane >> 4, ln16 = lane & 15;

    // ---- issue mask load immediately ----
    const int mv = (tid < Ln) ? mask[b * Ln + tid] : 0;

    // ---- tile0 globals (R0 <= 127: always < Ln) ----
    const float4* in4 = (const float4*)(input + (size_t)b * Ln * En);
    const float4* pe4 = (const float4*)pos_enc;
    const int rt0 = wave, rt1 = wave + 8;
    const int R0 = rt0 * 16 + ln16, R1 = rt1 * 16 + ln16;
    const int c4 = quad * 2;
    float4 x00 = in4[R0 * 16 + c4],     x01 = in4[R0 * 16 + c4 + 1];
    float4 x02 = in4[R0 * 16 + 8 + c4], x03 = in4[R0 * 16 + 8 + c4 + 1];
    float4 p00 = pe4[R0 * 16 + c4],     p01 = pe4[R0 * 16 + c4 + 1];
    float4 p02 = pe4[R0 * 16 + 8 + c4], p03 = pe4[R0 * 16 + 8 + c4 + 1];

    // ---- tile1 x prefetch only (pos loaded late; halves the prefetch registers) ----
    const bool t1ok = (rt1 < NT13);
    const bool v1   = t1ok && (R1 < Ln);
    float4 x10 = {0,0,0,0}, x11 = {0,0,0,0}, x12 = {0,0,0,0}, x13 = {0,0,0,0};
    if (v1) {
        x10 = in4[R1 * 16 + c4];     x11 = in4[R1 * 16 + c4 + 1];
        x12 = in4[R1 * 16 + 8 + c4]; x13 = in4[R1 * 16 + 8 + c4 + 1];
    }

    // ---- weight B-fragments (L2-hot) + biases ----
    f16x8 bfr[3][2][2];
    #pragma unroll
    for (int m = 0; m < 3; ++m) {
        const float* W = (m == 0) ? Wk : (m == 1) ? Wv : Wq;
        #pragma unroll
        for (int ct = 0; ct < 2; ++ct)
            #pragma unroll
            for (int ks = 0; ks < 2; ++ks) {
                const float4* wp = (const float4*)(W + (size_t)(hp * 32 + ct * 16 + ln16) * 64) + (ks * 8 + quad * 2);
                bfr[m][ct][ks] = pack8(wp[0], wp[1]);
            }
    }
    float bkv[2], bvv[2], bqv[2];
    #pragma unroll
    for (int ct = 0; ct < 2; ++ct) {
        int cg = hp * 32 + ct * 16 + ln16;
        bkv[ct] = bk[cg]; bvv[ct] = bv[cg]; bqv[ct] = bq[cg];
    }

    // ---- tile0: MFMA + epilogue ----
    {
        f16x8 af0[2];
        af0[0] = pack8s(x00, x01, p00, p01);
        af0[1] = pack8s(x02, x03, p02, p03);
        f32x4 acc[3][2];
        #pragma unroll
        for (int m = 0; m < 3; ++m)
            #pragma unroll
            for (int ct = 0; ct < 2; ++ct) acc[m][ct] = (f32x4){0,0,0,0};
        #pragma unroll
        for (int ks = 0; ks < 2; ++ks)
            #pragma unroll
            for (int m = 0; m < 3; ++m)
                #pragma unroll
                for (int ct = 0; ct < 2; ++ct)
                    acc[m][ct] = __builtin_amdgcn_mfma_f32_16x16x32_f16(af0[ks], bfr[m][ct][ks], acc[m][ct], 0, 0, 0);
        #pragma unroll
        for (int ct = 0; ct < 2; ++ct) {
            #pragma unroll
            for (int j = 0; j < 4; ++j) {
                int t = rt0 * 16 + quad * 4 + j;
                Kh[t * KS + ct * 16 + ln16] = (__f16)(acc[0][ct][j] + bkv[ct]);
                Qh[t * KS + ct * 16 + ln16] = (__f16)((acc[2][ct][j] + bqv[ct]) * 0.25f);
            }
            f16x4 vp;
            #pragma unroll
            for (int j = 0; j < 4; ++j) vp[j] = (__f16)(acc[1][ct][j] + bvv[ct]);
            *(f16x4*)(Vt + (ct * 16 + ln16) * VS + rt0 * 16 + quad * 4) = vp;
        }
    }
    // ---- tile1: load pos (L2-hot), MFMA + epilogue ----
    if (t1ok) {
        float4 p10 = {0,0,0,0}, p11 = {0,0,0,0}, p12 = {0,0,0,0}, p13 = {0,0,0,0};
        if (v1) {
            p10 = pe4[R1 * 16 + c4];     p11 = pe4[R1 * 16 + c4 + 1];
            p12 = pe4[R1 * 16 + 8 + c4]; p13 = pe4[R1 * 16 + 8 + c4 + 1];
        }
        f16x8 af1[2];
        af1[0] = pack8s(x10, x11, p10, p11);
        af1[1] = pack8s(x12, x13, p12, p13);
        f32x4 acc[3][2];
        #pragma unroll
        for (int m = 0; m < 3; ++m)
            #pragma unroll
            for (int ct = 0; ct < 2; ++ct) acc[m][ct] = (f32x4){0,0,0,0};
        #pragma unroll
        for (int ks = 0; ks < 2; ++ks)
            #pragma unroll
            for (int m = 0; m < 3; ++m)
                #pragma unroll
                for (int ct = 0; ct < 2; ++ct)
                    acc[m][ct] = __builtin_amdgcn_mfma_f32_16x16x32_f16(af1[ks], bfr[m][ct][ks], acc[m][ct], 0, 0, 0);
        #pragma unroll
        for (int ct = 0; ct < 2; ++ct) {
            #pragma unroll
            for (int j = 0; j < 4; ++j) {
                int t = rt1 * 16 + quad * 4 + j;
                Kh[t * KS + ct * 16 + ln16] = (__f16)(acc[0][ct][j] + bkv[ct]);
                Qh[t * KS + ct * 16 + ln16] = (__f16)((acc[2][ct][j] + bqv[ct]) * 0.25f);
            }
            f16x4 vp;
            #pragma unroll
            for (int j = 0; j < 4; ++j) vp[j] = (__f16)(acc[1][ct][j] + bvv[ct]);
            *(f16x4*)(Vt + (ct * 16 + ln16) * VS + rt1 * 16 + quad * 4) = vp;
        }
    }

    // ---- mask popcount ----
    int c = (mv != 0) ? 1 : 0;
    #pragma unroll
    for (int off = 32; off; off >>= 1) c += __shfl_down(c, off, 64);
    if (lane == 0) cnt_red[wave] = c;
    __syncthreads();   // proj LDS + cnt_red visible
    int len = 0;
    #pragma unroll
    for (int w = 0; w < 8; ++w) len += cnt_red[w];
    const int nt = (len + 15) >> 4;

    // ---- attention: head hl = wave>>2; pairs p = (wave&3), +4; kt-loop pipelined ----
    const int hl = wave >> 2;
    const int hoff = hl * 16;
    const int npair = (nt + 1) >> 1;
    f32x4 pool = {0.f, 0.f, 0.f, 0.f};

    for (int p = (wave & 3); p < npair; p += 4) {
        const int qt0 = 2 * p, qt1 = 2 * p + 1;
        const int qr1 = min(qt1 * 16 + ln16, RMAX - 1);
        const f16x4 qf0 = *(const f16x4*)(Qh + (qt0 * 16 + ln16) * KS + hoff + quad * 4);
        const f16x4 qf1 = *(const f16x4*)(Qh + qr1 * KS + hoff + quad * 4);
        f32x4 o20 = {0,0,0,0}, o21 = {0,0,0,0};
        float l0 = 0.f, l1 = 0.f;

        f16x4 kf = *(const f16x4*)(Kh + ln16 * KS + hoff + quad * 4);
        f16x4 vf = *(const f16x4*)(Vt + (hoff + ln16) * VS + quad * 4);

        for (int kt = 0; kt < nt - 1; ++kt) {     // full tiles
            const f16x4 kfn = *(const f16x4*)(Kh + ((kt + 1) * 16 + ln16) * KS + hoff + quad * 4);
            const f16x4 vfn = *(const f16x4*)(Vt + (hoff + ln16) * VS + (kt + 1) * 16 + quad * 4);
            f32x4 s0 = __builtin_amdgcn_mfma_f32_16x16x16f16(kf, qf0, (f32x4){0,0,0,0}, 0, 0, 0);
            f32x4 s1 = __builtin_amdgcn_mfma_f32_16x16x16f16(kf, qf1, (f32x4){0,0,0,0}, 0, 0, 0);
            f16x4 pf0, pf1;
            #pragma unroll
            for (int j = 0; j < 4; ++j) {
                float q0 = __expf(fminf(s0[j], 10.f));
                float q1 = __expf(fminf(s1[j], 10.f));
                l0 += q0; l1 += q1;
                pf0[j] = (__f16)q0; pf1[j] = (__f16)q1;
            }
            o20 = __builtin_amdgcn_mfma_f32_16x16x16f16(vf, pf0, o20, 0, 0, 0);
            o21 = __builtin_amdgcn_mfma_f32_16x16x16f16(vf, pf1, o21, 0, 0, 0);
            kf = kfn; vf = vfn;
        }
        {   // last tile: mask keys >= len
            const int kbase = (nt - 1) * 16 + quad * 4;
            f32x4 s0 = __builtin_amdgcn_mfma_f32_16x16x16f16(kf, qf0, (f32x4){0,0,0,0}, 0, 0, 0);
            f32x4 s1 = __builtin_amdgcn_mfma_f32_16x16x16f16(kf, qf1, (f32x4){0,0,0,0}, 0, 0, 0);
            f16x4 pf0, pf1;
            #pragma unroll
            for (int j = 0; j < 4; ++j) {
                const bool kok = (kbase + j) < len;
                float q0 = kok ? __expf(fminf(s0[j], 10.f)) : 0.f;
                float q1 = kok ? __expf(fminf(s1[j], 10.f)) : 0.f;
                l0 += q0; l1 += q1;
                pf0[j] = (__f16)q0; pf1[j] = (__f16)q1;
            }
            o20 = __builtin_amdgcn_mfma_f32_16x16x16f16(vf, pf0, o20, 0, 0, 0);
            o21 = __builtin_amdgcn_mfma_f32_16x16x16f16(vf, pf1, o21, 0, 0, 0);
        }

        l0 += __shfl_xor(l0, 16, 64); l0 += __shfl_xor(l0, 32, 64);
        l1 += __shfl_xor(l1, 16, 64); l1 += __shfl_xor(l1, 32, 64);
        const float rs0 = (qt0 * 16 + ln16 < len) ? 1.f / l0 : 0.f;
        const float rs1 = (qt1 * 16 + ln16 < len) ? 1.f / l1 : 0.f;
        #pragma unroll
        for (int j = 0; j < 4; ++j)
            pool[j] = fmaf(o20[j], rs0, fmaf(o21[j], rs1, pool[j]));
    }

    // ---- reduce pool over 16 q-lanes; combine 4 waves/head ----
    #pragma unroll
    for (int j = 0; j < 4; ++j) {
        #pragma unroll
        for (int off = 1; off < 16; off <<= 1) pool[j] += __shfl_xor(pool[j], off, 64);
    }
    if (ln16 == 0) {
        #pragma unroll
        for (int j = 0; j < 4; ++j) red[wave][quad * 4 + j] = pool[j];
    }
    __syncthreads();
    if (tid < 32) {
        int hl2 = tid >> 4, vd = tid & 15;
        float sres = red[hl2 * 4][vd] + red[hl2 * 4 + 1][vd]
                   + red[hl2 * 4 + 2][vd] + red[hl2 * 4 + 3][vd];
        ph[tid] = sres / ((float)len + 1e-8f);   // this block's half of pooled[b]
    }
    __syncthreads();

    // ---- fused final projection: partial out[b,e] over i in [hp*32, hp*32+32) ----
    if (tid < 64) {
        const int e = tid;
        const float* wr = Wf + (size_t)e * 64 + hp * 32;
        float a = (hp == 0) ? bf_[e] : 0.f;
        #pragma unroll
        for (int i = 0; i < 32; ++i) a = fmaf(wr[i], ph[i], a);
        atomicAdd(out + b * En + e, a);
    }
}

extern "C" void kernel_launch(void* const* d_in, const int* in_sizes, int n_in,
                              void* d_out, int out_size, void* d_ws, size_t ws_size,
                              hipStream_t stream) {
    const float* input   = (const float*)d_in[0];
    const int*   mask    = (const int*)  d_in[1];
    const float* pos_enc = (const float*)d_in[2];
    const float* Wk      = (const float*)d_in[3];
    const float* bk      = (const float*)d_in[4];
    const float* Wv      = (const float*)d_in[5];
    const float* bv      = (const float*)d_in[6];
    const float* Wq      = (const float*)d_in[7];
    const float* bq      = (const float*)d_in[8];
    const float* Wf      = (const float*)d_in[9];
    const float* bf      = (const float*)d_in[10];

    float* out = (float*)d_out;
    hipMemsetAsync(out, 0, (size_t)Bn * En * sizeof(float), stream);   // zero accumulator

    fused_kernel<<<Bn * 2, 512, 0, stream>>>(input, mask, pos_enc,
                                             Wk, bk, Wv, bv, Wq, bq, Wf, bf, out);
}

// Round 10
// 125.816 us; speedup vs baseline: 1.3011x; 1.1835x over previous
//
#include <hip/hip_runtime.h>
#include <hip/hip_fp16.h>
#include <math.h>

#define Bn 512
#define Ln 200
#define En 64
#define Hn 4
#define Dn 16
#define NT13 13           // ceil(200/16)
#define RMAX 208          // 13*16
#define XS 72             // xw row stride (halves): 144 B (16B-mult for b128)
#define KS 36             // Kh/Qh row stride (halves): 72 B (18 words: 16 lanes -> 16 banks)
#define VS 212            // Vt row stride (halves): 424 B (106 words: conflict-free)
#define QSC 0.36067376022224085f   // 0.25 * log2(e): folds softmax exp into 2^x

typedef _Float16 __f16;
typedef __f16 f16x4 __attribute__((ext_vector_type(4)));
typedef __f16 f16x8 __attribute__((ext_vector_type(8)));
typedef float f32x4 __attribute__((ext_vector_type(4)));

#if __has_builtin(__builtin_amdgcn_exp2f)
__device__ __forceinline__ float fexp2(float x) { return __builtin_amdgcn_exp2f(x); }
#else
__device__ __forceinline__ float fexp2(float x) { return exp2f(x); }
#endif

__device__ __forceinline__ f16x8 pack8(float4 a, float4 b) {
    f16x8 r;
    r[0] = (__f16)a.x; r[1] = (__f16)a.y; r[2] = (__f16)a.z; r[3] = (__f16)a.w;
    r[4] = (__f16)b.x; r[5] = (__f16)b.y; r[6] = (__f16)b.z; r[7] = (__f16)b.w;
    return r;
}

// ============ Fully fused: proj + attention + pool + Wf. Block = (b, head-pair), 256 thr ============
// R7 structure (proven best): 2048 thin blocks, JIT per-wave coalesced LDS staging of x,
// ONE mid-kernel barrier. New vs R7: (a) attention runs a QUAD of q-tiles per wave round
// (4 independent MFMA/exp chains share each K/V read -> half the serial kt-loop trips),
// (b) exp via native 2^x (scale folded into Q), (c) Wf epilogue fused (atomicAdd, out pre-zeroed).
__global__ __launch_bounds__(256, 3) void fused_kernel(
    const float* __restrict__ input, const int* __restrict__ mask,
    const float* __restrict__ pos_enc,
    const float* __restrict__ Wk, const float* __restrict__ bk,
    const float* __restrict__ Wv, const float* __restrict__ bv,
    const float* __restrict__ Wq, const float* __restrict__ bq,
    const float* __restrict__ Wf, const float* __restrict__ bf_,
    float* __restrict__ out)
{
    __shared__ __align__(16) __f16 xw[4][16 * XS];  //  9.2 KB per-wave JIT tiles
    __shared__ __align__(16) __f16 Kh[RMAX * KS];   // 15.0 KB  K[t][2*16]
    __shared__ __align__(16) __f16 Qh[RMAX * KS];   // 15.0 KB  Q[t][2*16] (pre-scaled QSC)
    __shared__ __align__(16) __f16 Vt[32 * VS];     // 13.6 KB  V^T[vd][t]
    __shared__ float red[4][16];
    __shared__ float ph[32];
    __shared__ int cnt_red[4];

    const int tid  = threadIdx.x;
    const int b    = blockIdx.x >> 1, hp = blockIdx.x & 1;
    const int wave = tid >> 6, lane = tid & 63;
    const int quad = lane >> 4, ln16 = lane & 15;

    // ---- mask loads issued first ----
    int c = 0;
    for (int t = tid; t < Ln; t += 256) c += (mask[b * Ln + t] != 0) ? 1 : 0;

    // ---- weight B-fragments (L2-hot) + biases ----
    f16x8 bfr[3][2][2];
    #pragma unroll
    for (int m = 0; m < 3; ++m) {
        const float* W = (m == 0) ? Wk : (m == 1) ? Wv : Wq;
        #pragma unroll
        for (int ct = 0; ct < 2; ++ct)
            #pragma unroll
            for (int ks = 0; ks < 2; ++ks) {
                const float4* wp = (const float4*)(W + (size_t)(hp * 32 + ct * 16 + ln16) * 64) + (ks * 8 + quad * 2);
                bfr[m][ct][ks] = pack8(wp[0], wp[1]);
            }
    }
    float bkv[2], bvv[2], bqv[2];
    #pragma unroll
    for (int ct = 0; ct < 2; ++ct) {
        int cg = hp * 32 + ct * 16 + ln16;
        bkv[ct] = bk[cg]; bvv[ct] = bv[cg]; bqv[ct] = bq[cg];
    }

    // ---- projection over 13 tiles, JIT-staged per wave (coalesced float4 loads) ----
    const float4* in4 = (const float4*)(input + (size_t)b * Ln * En);
    const float4* pe4 = (const float4*)pos_enc;
    __f16* myx = xw[wave];

    for (int rt = wave; rt < NT13; rt += 4) {
        #pragma unroll
        for (int i = 0; i < 4; ++i) {
            const int gi = lane + (i << 6);
            const int r = gi >> 4, c4 = gi & 15;
            const int R = rt * 16 + r;
            float4 xv = {0,0,0,0}, pv = {0,0,0,0};
            if (R < Ln) { xv = in4[R * 16 + c4]; pv = pe4[R * 16 + c4]; }
            f16x4 hx;
            hx[0] = (__f16)(xv.x + pv.x); hx[1] = (__f16)(xv.y + pv.y);
            hx[2] = (__f16)(xv.z + pv.z); hx[3] = (__f16)(xv.w + pv.w);
            *(f16x4*)(myx + r * XS + c4 * 4) = hx;   // same-wave write->read
        }

        f16x8 af[2];
        #pragma unroll
        for (int ks = 0; ks < 2; ++ks)
            af[ks] = *(const f16x8*)(myx + ln16 * XS + ks * 32 + quad * 8);

        f32x4 acc[3][2];
        #pragma unroll
        for (int m = 0; m < 3; ++m)
            #pragma unroll
            for (int ct = 0; ct < 2; ++ct) acc[m][ct] = (f32x4){0,0,0,0};
        #pragma unroll
        for (int ks = 0; ks < 2; ++ks)
            #pragma unroll
            for (int m = 0; m < 3; ++m)
                #pragma unroll
                for (int ct = 0; ct < 2; ++ct)
                    acc[m][ct] = __builtin_amdgcn_mfma_f32_16x16x32_f16(af[ks], bfr[m][ct][ks], acc[m][ct], 0, 0, 0);

        #pragma unroll
        for (int ct = 0; ct < 2; ++ct) {
            #pragma unroll
            for (int j = 0; j < 4; ++j) {
                int t = rt * 16 + quad * 4 + j;
                Kh[t * KS + ct * 16 + ln16] = (__f16)(acc[0][ct][j] + bkv[ct]);
                Qh[t * KS + ct * 16 + ln16] = (__f16)((acc[2][ct][j] + bqv[ct]) * QSC);
            }
            f16x4 vp;
            #pragma unroll
            for (int j = 0; j < 4; ++j) vp[j] = (__f16)(acc[1][ct][j] + bvv[ct]);
            *(f16x4*)(Vt + (ct * 16 + ln16) * VS + rt * 16 + quad * 4) = vp;
        }
    }

    // ---- mask popcount ----
    #pragma unroll
    for (int off = 32; off; off >>= 1) c += __shfl_down(c, off, 64);
    if (lane == 0) cnt_red[wave] = c;
    __syncthreads();   // proj LDS + cnt_red visible
    const int len = cnt_red[0] + cnt_red[1] + cnt_red[2] + cnt_red[3];
    const int nt = (len + 15) >> 4;

    // ---- attention: head hl = wave>>1; QUAD of q-tiles per round g = (wave&1), +2 ----
    // 4 independent MFMA/exp chains share each K/V fragment read; kt-trips halve vs pairs.
    const int hl = wave >> 1;
    const int hoff = hl * 16;
    const int nquad = (nt + 3) >> 2;
    f32x4 pool = {0.f, 0.f, 0.f, 0.f};

    for (int g = (wave & 1); g < nquad; g += 2) {
        const int qt0 = 4 * g;
        f16x4 qf[4];
        #pragma unroll
        for (int i = 0; i < 4; ++i) {
            int qr = min((qt0 + i) * 16 + ln16, RMAX - 1);
            qf[i] = *(const f16x4*)(Qh + qr * KS + hoff + quad * 4);
        }
        f32x4 o2[4];
        float l[4] = {0.f, 0.f, 0.f, 0.f};
        #pragma unroll
        for (int i = 0; i < 4; ++i) o2[i] = (f32x4){0,0,0,0};

        f16x4 kf = *(const f16x4*)(Kh + ln16 * KS + hoff + quad * 4);
        f16x4 vf = *(const f16x4*)(Vt + (hoff + ln16) * VS + quad * 4);

        for (int kt = 0; kt < nt - 1; ++kt) {     // full tiles: all keys valid
            const f16x4 kfn = *(const f16x4*)(Kh + ((kt + 1) * 16 + ln16) * KS + hoff + quad * 4);
            const f16x4 vfn = *(const f16x4*)(Vt + (hoff + ln16) * VS + (kt + 1) * 16 + quad * 4);
            f32x4 s[4];
            #pragma unroll
            for (int i = 0; i < 4; ++i)
                s[i] = __builtin_amdgcn_mfma_f32_16x16x16f16(kf, qf[i], (f32x4){0,0,0,0}, 0, 0, 0);
            f16x4 pf[4];
            #pragma unroll
            for (int i = 0; i < 4; ++i) {
                #pragma unroll
                for (int j = 0; j < 4; ++j) {
                    float p = fexp2(fminf(s[i][j], 14.5f));   // 2^14.5 < fp16 max
                    l[i] += p;
                    pf[i][j] = (__f16)p;
                }
            }
            #pragma unroll
            for (int i = 0; i < 4; ++i)
                o2[i] = __builtin_amdgcn_mfma_f32_16x16x16f16(vf, pf[i], o2[i], 0, 0, 0);
            kf = kfn; vf = vfn;
        }
        {   // last tile: mask keys >= len
            const int kbase = (nt - 1) * 16 + quad * 4;
            f32x4 s[4];
            #pragma unroll
            for (int i = 0; i < 4; ++i)
                s[i] = __builtin_amdgcn_mfma_f32_16x16x16f16(kf, qf[i], (f32x4){0,0,0,0}, 0, 0, 0);
            f16x4 pf[4];
            #pragma unroll
            for (int i = 0; i < 4; ++i) {
                #pragma unroll
                for (int j = 0; j < 4; ++j) {
                    const bool kok = (kbase + j) < len;
                    float p = kok ? fexp2(fminf(s[i][j], 14.5f)) : 0.f;
                    l[i] += p;
                    pf[i][j] = (__f16)p;
                }
            }
            #pragma unroll
            for (int i = 0; i < 4; ++i)
                o2[i] = __builtin_amdgcn_mfma_f32_16x16x16f16(vf, pf[i], o2[i], 0, 0, 0);
        }

        #pragma unroll
        for (int i = 0; i < 4; ++i) {
            l[i] += __shfl_xor(l[i], 16, 64);
            l[i] += __shfl_xor(l[i], 32, 64);
            const float rs = ((qt0 + i) * 16 + ln16 < len) ? 1.f / l[i] : 0.f;
            #pragma unroll
            for (int j = 0; j < 4; ++j) pool[j] = fmaf(o2[i][j], rs, pool[j]);
        }
    }

    // ---- reduce pool over 16 q-lanes; combine 2 waves/head ----
    #pragma unroll
    for (int j = 0; j < 4; ++j) {
        #pragma unroll
        for (int off = 1; off < 16; off <<= 1) pool[j] += __shfl_xor(pool[j], off, 64);
    }
    if (ln16 == 0) {
        #pragma unroll
        for (int j = 0; j < 4; ++j) red[wave][quad * 4 + j] = pool[j];
    }
    __syncthreads();
    if (tid < 32) {
        int hl2 = tid >> 4, vd = tid & 15;
        float sres = red[hl2 * 2][vd] + red[hl2 * 2 + 1][vd];
        ph[tid] = sres / ((float)len + 1e-8f);   // this block's half of pooled[b]
    }
    __syncthreads();

    // ---- fused final projection: partial out[b,e] over i in [hp*32, hp*32+32) ----
    if (tid < 64) {
        const int e = tid;
        const float* wr = Wf + (size_t)e * 64 + hp * 32;
        float a = (hp == 0) ? bf_[e] : 0.f;
        #pragma unroll
        for (int i = 0; i < 32; ++i) a = fmaf(wr[i], ph[i], a);
        atomicAdd(out + b * En + e, a);
    }
}

extern "C" void kernel_launch(void* const* d_in, const int* in_sizes, int n_in,
                              void* d_out, int out_size, void* d_ws, size_t ws_size,
                              hipStream_t stream) {
    const float* input   = (const float*)d_in[0];
    const int*   mask    = (const int*)  d_in[1];
    const float* pos_enc = (const float*)d_in[2];
    const float* Wk      = (const float*)d_in[3];
    const float* bk      = (const float*)d_in[4];
    const float* Wv      = (const float*)d_in[5];
    const float* bv      = (const float*)d_in[6];
    const float* Wq      = (const float*)d_in[7];
    const float* bq      = (const float*)d_in[8];
    const float* Wf      = (const float*)d_in[9];
    const float* bf      = (const float*)d_in[10];

    float* out = (float*)d_out;
    hipMemsetAsync(out, 0, (size_t)Bn * En * sizeof(float), stream);   // zero accumulator

    fused_kernel<<<Bn * 2, 256, 0, stream>>>(input, mask, pos_enc,
                                             Wk, bk, Wv, bv, Wq, bq, Wf, bf, out);
}

// Round 11
// 123.676 us; speedup vs baseline: 1.3236x; 1.0173x over previous
//
#include <hip/hip_runtime.h>
#include <hip/hip_fp16.h>
#include <math.h>

#define Bn 512
#define Ln 200
#define En 64
#define Hn 4
#define Dn 16
#define NT13 13           // ceil(200/16)
#define KS2 34            // Kh row stride (halves): 68 B, 17 words (odd -> spread banks)
#define QS2 32            // Qh row stride (halves): compact (read once per round; conflicts ok)
#define VS2 200           // Vt row stride (halves): 100 words (2-way = free)
#define QSC 0.36067376022224085f   // 0.25 * log2(e): folds softmax exp into 2^x

typedef _Float16 __f16;
typedef __f16 f16x4 __attribute__((ext_vector_type(4)));
typedef __f16 f16x8 __attribute__((ext_vector_type(8)));
typedef float f32x4 __attribute__((ext_vector_type(4)));

#if __has_builtin(__builtin_amdgcn_exp2f)
__device__ __forceinline__ float fexp2(float x) { return __builtin_amdgcn_exp2f(x); }
#else
__device__ __forceinline__ float fexp2(float x) { return exp2f(x); }
#endif

__device__ __forceinline__ f16x8 pack8s(float4 a, float4 b, float4 pa, float4 pb) {
    f16x8 r;
    r[0] = (__f16)(a.x + pa.x); r[1] = (__f16)(a.y + pa.y);
    r[2] = (__f16)(a.z + pa.z); r[3] = (__f16)(a.w + pa.w);
    r[4] = (__f16)(b.x + pb.x); r[5] = (__f16)(b.y + pb.y);
    r[6] = (__f16)(b.z + pb.z); r[7] = (__f16)(b.w + pb.w);
    return r;
}
__device__ __forceinline__ f16x8 pack8(float4 a, float4 b) {
    f16x8 r;
    r[0] = (__f16)a.x; r[1] = (__f16)a.y; r[2] = (__f16)a.z; r[3] = (__f16)a.w;
    r[4] = (__f16)b.x; r[5] = (__f16)b.y; r[6] = (__f16)b.z; r[7] = (__f16)b.w;
    return r;
}

// ============ Fully fused: proj + attention + pool + Wf. Block = (b, head-pair), 256 thr ============
// R10 structure with LDS cut 53.2 -> <40 KB for 4 blocks/CU (16 waves: the latency-hiding lever):
//  - no x staging buffer: lanes load A-fragments directly from global (L1 absorbs the 32B-chunk
//    row pattern; pos_enc is L2-hot),
//  - Kh/Qh/Vt sized to exactly 200 rows/cols: writes guarded t<200; reads clamped min(.,199) --
//    clamped positions are keys >= len whose p=0 annihilates garbage in the PV MFMA.
// Attention: quad of q-tiles per wave round (4 indep MFMA/exp chains share each K/V read),
// exp via native 2^x (scale folded into Q), Wf epilogue fused (atomicAdd, out pre-zeroed).
__global__ __launch_bounds__(256, 4) void fused_kernel(
    const float* __restrict__ input, const int* __restrict__ mask,
    const float* __restrict__ pos_enc,
    const float* __restrict__ Wk, const float* __restrict__ bk,
    const float* __restrict__ Wv, const float* __restrict__ bv,
    const float* __restrict__ Wq, const float* __restrict__ bq,
    const float* __restrict__ Wf, const float* __restrict__ bf_,
    float* __restrict__ out)
{
    __shared__ __align__(16) __f16 Kh[Ln * KS2];    // 13.6 KB  K[t][2*16]
    __shared__ __align__(16) __f16 Qh[Ln * QS2];    // 12.8 KB  Q[t][2*16] (pre-scaled QSC)
    __shared__ __align__(16) __f16 Vt[32 * VS2];    // 12.8 KB  V^T[vd][t]
    __shared__ float red[4][16];
    __shared__ float ph[32];
    __shared__ int cnt_red[4];

    const int tid  = threadIdx.x;
    const int b    = blockIdx.x >> 1, hp = blockIdx.x & 1;
    const int wave = tid >> 6, lane = tid & 63;
    const int quad = lane >> 4, ln16 = lane & 15;

    // ---- mask loads issued first ----
    int c = 0;
    for (int t = tid; t < Ln; t += 256) c += (mask[b * Ln + t] != 0) ? 1 : 0;

    // ---- weight B-fragments (L2-hot) + biases ----
    f16x8 bfr[3][2][2];
    #pragma unroll
    for (int m = 0; m < 3; ++m) {
        const float* W = (m == 0) ? Wk : (m == 1) ? Wv : Wq;
        #pragma unroll
        for (int ct = 0; ct < 2; ++ct)
            #pragma unroll
            for (int ks = 0; ks < 2; ++ks) {
                const float4* wp = (const float4*)(W + (size_t)(hp * 32 + ct * 16 + ln16) * 64) + (ks * 8 + quad * 2);
                bfr[m][ct][ks] = pack8(wp[0], wp[1]);
            }
    }
    float bkv[2], bvv[2], bqv[2];
    #pragma unroll
    for (int ct = 0; ct < 2; ++ct) {
        int cg = hp * 32 + ct * 16 + ln16;
        bkv[ct] = bk[cg]; bvv[ct] = bv[cg]; bqv[ct] = bq[cg];
    }

    // ---- projection over 13 tiles; A-frags loaded directly from global ----
    const float4* in4 = (const float4*)(input + (size_t)b * Ln * En);
    const float4* pe4 = (const float4*)pos_enc;

    for (int rt = wave; rt < NT13; rt += 4) {
        const int R = rt * 16 + ln16;
        const bool rok = (R < Ln);
        f16x8 af[2];
        #pragma unroll
        for (int ks = 0; ks < 2; ++ks) {
            float4 xa = {0,0,0,0}, xb = {0,0,0,0}, pa = {0,0,0,0}, pb = {0,0,0,0};
            if (rok) {
                const int o4 = R * 16 + ks * 8 + quad * 2;
                xa = in4[o4]; xb = in4[o4 + 1];
                pa = pe4[o4 - R * 16 + (R % Ln) * 16];  // R < Ln here, so same index
                pb = pe4[o4 - R * 16 + (R % Ln) * 16 + 1];
            }
            af[ks] = pack8s(xa, xb, pa, pb);
        }

        f32x4 acc[3][2];
        #pragma unroll
        for (int m = 0; m < 3; ++m)
            #pragma unroll
            for (int ct = 0; ct < 2; ++ct) acc[m][ct] = (f32x4){0,0,0,0};
        #pragma unroll
        for (int ks = 0; ks < 2; ++ks)
            #pragma unroll
            for (int m = 0; m < 3; ++m)
                #pragma unroll
                for (int ct = 0; ct < 2; ++ct)
                    acc[m][ct] = __builtin_amdgcn_mfma_f32_16x16x32_f16(af[ks], bfr[m][ct][ks], acc[m][ct], 0, 0, 0);

        #pragma unroll
        for (int ct = 0; ct < 2; ++ct) {
            #pragma unroll
            for (int j = 0; j < 4; ++j) {
                const int t = rt * 16 + quad * 4 + j;
                if (t < Ln) {
                    Kh[t * KS2 + ct * 16 + ln16] = (__f16)(acc[0][ct][j] + bkv[ct]);
                    Qh[t * QS2 + ct * 16 + ln16] = (__f16)((acc[2][ct][j] + bqv[ct]) * QSC);
                }
            }
            const int vc0 = rt * 16 + quad * 4;
            if (vc0 < Ln) {
                f16x4 vp;
                #pragma unroll
                for (int j = 0; j < 4; ++j) vp[j] = (__f16)(acc[1][ct][j] + bvv[ct]);
                *(f16x4*)(Vt + (ct * 16 + ln16) * VS2 + vc0) = vp;
            }
        }
    }

    // ---- mask popcount ----
    #pragma unroll
    for (int off = 32; off; off >>= 1) c += __shfl_down(c, off, 64);
    if (lane == 0) cnt_red[wave] = c;
    __syncthreads();   // proj LDS + cnt_red visible
    const int len = cnt_red[0] + cnt_red[1] + cnt_red[2] + cnt_red[3];
    const int nt = (len + 15) >> 4;

    // ---- attention: head hl = wave>>1; QUAD of q-tiles per round g = (wave&1), +2 ----
    const int hl = wave >> 1;
    const int hoff = hl * 16;
    const int nquad = (nt + 3) >> 2;
    f32x4 pool = {0.f, 0.f, 0.f, 0.f};

    for (int g = (wave & 1); g < nquad; g += 2) {
        const int qt0 = 4 * g;
        f16x4 qf[4];
        #pragma unroll
        for (int i = 0; i < 4; ++i) {
            int qr = min((qt0 + i) * 16 + ln16, Ln - 1);
            qf[i] = *(const f16x4*)(Qh + qr * QS2 + hoff + quad * 4);
        }
        f32x4 o2[4];
        float l[4] = {0.f, 0.f, 0.f, 0.f};
        #pragma unroll
        for (int i = 0; i < 4; ++i) o2[i] = (f32x4){0,0,0,0};

        f16x4 kf = *(const f16x4*)(Kh + ln16 * KS2 + hoff + quad * 4);
        f16x4 vf = *(const f16x4*)(Vt + (hoff + ln16) * VS2 + quad * 4);

        for (int kt = 0; kt < nt - 1; ++kt) {     // full tiles: all keys valid
            const int krn = min((kt + 1) * 16 + ln16, Ln - 1);
            const int vcn = min((kt + 1) * 16 + quad * 4, Ln - 4);
            const f16x4 kfn = *(const f16x4*)(Kh + krn * KS2 + hoff + quad * 4);
            const f16x4 vfn = *(const f16x4*)(Vt + (hoff + ln16) * VS2 + vcn);
            f32x4 s[4];
            #pragma unroll
            for (int i = 0; i < 4; ++i)
                s[i] = __builtin_amdgcn_mfma_f32_16x16x16f16(kf, qf[i], (f32x4){0,0,0,0}, 0, 0, 0);
            f16x4 pf[4];
            #pragma unroll
            for (int i = 0; i < 4; ++i) {
                #pragma unroll
                for (int j = 0; j < 4; ++j) {
                    float p = fexp2(fminf(s[i][j], 14.5f));   // 2^14.5 < fp16 max
                    l[i] += p;
                    pf[i][j] = (__f16)p;
                }
            }
            #pragma unroll
            for (int i = 0; i < 4; ++i)
                o2[i] = __builtin_amdgcn_mfma_f32_16x16x16f16(vf, pf[i], o2[i], 0, 0, 0);
            kf = kfn; vf = vfn;
        }
        {   // last tile: mask keys >= len (garbage from clamped rows is annihilated by p=0)
            const int kbase = (nt - 1) * 16 + quad * 4;
            f32x4 s[4];
            #pragma unroll
            for (int i = 0; i < 4; ++i)
                s[i] = __builtin_amdgcn_mfma_f32_16x16x16f16(kf, qf[i], (f32x4){0,0,0,0}, 0, 0, 0);
            f16x4 pf[4];
            #pragma unroll
            for (int i = 0; i < 4; ++i) {
                #pragma unroll
                for (int j = 0; j < 4; ++j) {
                    const bool kok = (kbase + j) < len;
                    float p = kok ? fexp2(fminf(s[i][j], 14.5f)) : 0.f;
                    l[i] += p;
                    pf[i][j] = (__f16)p;
                }
            }
            #pragma unroll
            for (int i = 0; i < 4; ++i)
                o2[i] = __builtin_amdgcn_mfma_f32_16x16x16f16(vf, pf[i], o2[i], 0, 0, 0);
        }

        #pragma unroll
        for (int i = 0; i < 4; ++i) {
            l[i] += __shfl_xor(l[i], 16, 64);
            l[i] += __shfl_xor(l[i], 32, 64);
            const float rs = ((qt0 + i) * 16 + ln16 < len) ? 1.f / l[i] : 0.f;
            #pragma unroll
            for (int j = 0; j < 4; ++j) pool[j] = fmaf(o2[i][j], rs, pool[j]);
        }
    }

    // ---- reduce pool over 16 q-lanes; combine 2 waves/head ----
    #pragma unroll
    for (int j = 0; j < 4; ++j) {
        #pragma unroll
        for (int off = 1; off < 16; off <<= 1) pool[j] += __shfl_xor(pool[j], off, 64);
    }
    if (ln16 == 0) {
        #pragma unroll
        for (int j = 0; j < 4; ++j) red[wave][quad * 4 + j] = pool[j];
    }
    __syncthreads();
    if (tid < 32) {
        int hl2 = tid >> 4, vd = tid & 15;
        float sres = red[hl2 * 2][vd] + red[hl2 * 2 + 1][vd];
        ph[tid] = sres / ((float)len + 1e-8f);   // this block's half of pooled[b]
    }
    __syncthreads();

    // ---- fused final projection: partial out[b,e] over i in [hp*32, hp*32+32) ----
    if (tid < 64) {
        const int e = tid;
        const float* wr = Wf + (size_t)e * 64 + hp * 32;
        float a = (hp == 0) ? bf_[e] : 0.f;
        #pragma unroll
        for (int i = 0; i < 32; ++i) a = fmaf(wr[i], ph[i], a);
        atomicAdd(out + b * En + e, a);
    }
}

extern "C" void kernel_launch(void* const* d_in, const int* in_sizes, int n_in,
                              void* d_out, int out_size, void* d_ws, size_t ws_size,
                              hipStream_t stream) {
    const float* input   = (const float*)d_in[0];
    const int*   mask    = (const int*)  d_in[1];
    const float* pos_enc = (const float*)d_in[2];
    const float* Wk      = (const float*)d_in[3];
    const float* bk      = (const float*)d_in[4];
    const float* Wv      = (const float*)d_in[5];
    const float* bv      = (const float*)d_in[6];
    const float* Wq      = (const float*)d_in[7];
    const float* bq      = (const float*)d_in[8];
    const float* Wf      = (const float*)d_in[9];
    const float* bf      = (const float*)d_in[10];

    float* out = (float*)d_out;
    hipMemsetAsync(out, 0, (size_t)Bn * En * sizeof(float), stream);   // zero accumulator

    fused_kernel<<<Bn * 2, 256, 0, stream>>>(input, mask, pos_enc,
                                             Wk, bk, Wv, bv, Wq, bq, Wf, bf, out);
}